// Round 14
// baseline (2373.959 us; speedup 1.0000x reference)
//
#include <hip/hip_runtime.h>
#include <hip/hip_cooperative_groups.h>
#include <math.h>

namespace cg = cooperative_groups;

#define NN 4096
#define WW 12
#define HH 256
#define PP 10
#define EE 131072
#define HS 262144
#define HMASK (HS-1)
#define TS 192           // table intervals; pair-table = 2.37 MB, L2-resident
#define TA 8.0f          // table half-domain: a in [-TA, TA]
#define RS 22            // ring stride: 12 init cols + 10 pred cols (append-only)
#define NBLK 256         // persistent grid: 1 block/CU, cooperative

typedef __attribute__((ext_vector_type(8))) _Float16 half8v;  // 8 x fp16 (A/B frag)
typedef __attribute__((ext_vector_type(4))) _Float16 half4v;
typedef __attribute__((ext_vector_type(4))) float f32x4;      // C/D frag

__device__ __forceinline__ float fast_tanh(float x){
  float e = __expf(2.0f*x);
  return 1.0f - 2.0f/(e+1.0f);   // exact identity (e^2x-1)/(e^2x+1)
}
__device__ __forceinline__ float fast_sigmoid(float x){
  return 1.0f/(1.0f+__expf(-x));
}

// ---------------- setup kernels ----------------

__global__ void k_init(const float* __restrict__ x, int* keys, int* midx,
                       float* deg, int* cnt, float* ring, int* count){
  int t = blockIdx.x*256 + threadIdx.x;        // 262144 threads
  int i4 = t*4;
  if (i4 < HS){
    int4 m1 = make_int4(-1,-1,-1,-1);
    *(int4*)&keys[i4] = m1;
    *(int4*)&midx[i4] = m1;
  }
  if (i4 < NN*WW){
    #pragma unroll
    for (int j = 0; j < 4; ++j){
      int i = i4 + j;
      int n = i/WW, w = i - n*WW;
      ring[n*RS + w] = x[i];
    }
  }
  if (t < NN){ deg[t] = 0.0f; cnt[t] = 0; }
  if (t == 0) *count = 0;
}

// dedupe: numpy fancy assignment => last (max-index) edge wins per (src,dst)
__global__ void k_insert(const int* __restrict__ ei, int* keys, int* midx){
  int e = blockIdx.x*256 + threadIdx.x;
  if (e >= EE) return;
  int key = ei[e]*NN + ei[EE+e];
  unsigned h = (((unsigned)key)*2654435761u >> 14) & HMASK;
  for(;;){
    int k = keys[h];
    if (k == key){ atomicMax(&midx[h], e); return; }
    if (k == -1){
      int old = atomicCAS(&keys[h], -1, key);
      if (old == -1 || old == key){ atomicMax(&midx[h], e); return; }
    }
    h = (h+1) & HMASK;
  }
}

__global__ void k_compact(const int* __restrict__ ei, const float* __restrict__ ew,
                          const int* __restrict__ keys, const int* __restrict__ midx,
                          int* wsrc, int* wdst, float* wwt,
                          float* deg, int* cnt, int* count){
  int e = blockIdx.x*256 + threadIdx.x;
  if (e >= EE) return;
  int src = ei[e], dst = ei[EE+e];
  int key = src*NN + dst;
  unsigned h = (((unsigned)key)*2654435761u >> 14) & HMASK;
  while (keys[h] != key) h = (h+1) & HMASK;
  if (midx[h] == e){            // this edge is the winner for (src,dst)
    int p = atomicAdd(count, 1);
    wsrc[p] = src; wdst[p] = dst; wwt[p] = ew[e];
    atomicAdd(&deg[src], ew[e]);
    atomicAdd(&cnt[dst], 1);
  }
}

__global__ __launch_bounds__(1024) void k_scan(const int* __restrict__ cnt,
                                               int* row_start, int* fill){
  __shared__ int sd[NN];
  int tid = threadIdx.x;
  for (int i = tid; i < NN; i += 1024) sd[i] = cnt[i];
  __syncthreads();
  for (int off = 1; off < NN; off <<= 1){
    int v[4];
    #pragma unroll
    for (int r = 0; r < 4; ++r){
      int i = tid + r*1024;
      v[r] = (i >= off) ? sd[i-off] : 0;
    }
    __syncthreads();
    #pragma unroll
    for (int r = 0; r < 4; ++r) sd[tid + r*1024] += v[r];
    __syncthreads();
  }
  for (int i = tid; i < NN; i += 1024){
    int incl = sd[i];
    row_start[i+1] = incl;
    fill[i] = incl - cnt[i];
  }
  if (tid == 0) row_start[0] = 0;
}

// scatter + inline coef = wwt * d[src] * d[dst], d = 1/sqrt(deg+1)
__global__ void k_scatter(const int* __restrict__ wsrc, const int* __restrict__ wdst,
                          const float* __restrict__ wwt, const float* __restrict__ deg,
                          int* fill, int* csr_src, float* csr_cf,
                          const int* __restrict__ count){
  int p = blockIdx.x*256 + threadIdx.x;
  if (p >= *count) return;
  int s = wsrc[p], d = wdst[p];
  float c = wwt[p] * (1.0f/sqrtf(deg[s]+1.0f)) * (1.0f/sqrtf(deg[d]+1.0f));
  int pos = atomicAdd(&fill[d], 1);
  csr_src[pos] = s;
  csr_cf[pos] = c;
}

// table build (z<12) + weight pack (z==12), fused into one dispatch.
// tabp layout: [w][s][h] pair (f16 tab[s][h], f16 tab[s+1][h]) -> 4 B/entry.
__global__ __launch_bounds__(256) void k_tab(const float* __restrict__ gcn_w,
                                             const float* __restrict__ ta_w,
                                             const float* __restrict__ w_ih,
                                             const float* __restrict__ w_hh,
                                             _Float16* __restrict__ tabp,
                                             _Float16* __restrict__ wp){
  int tid = threadIdx.x;
  int w  = blockIdx.z;
  if (w == 12){
    // ---- weight pack: 16 slice-blocks x 256 thr x 16 octets ----
    int sb = blockIdx.y*4 + blockIdx.x;       // 0..15
    #pragma unroll
    for (int k = 0; k < 16; ++k){
      int idx = sb*4096 + k*256 + tid;
      int lane = idx & 63;
      int rest = idx >> 6;
      int ct = rest & 15; rest >>= 4;
      int g  = rest & 3;
      int ks = rest >> 2;
      int col = ct*16 + (lane & 15);
      int kb  = ks*32 + (lane >> 4)*8;
      _Float16 w8[8];
      #pragma unroll
      for (int j = 0; j < 8; ++j){
        int kk = kb + j;
        float v;
        if      (g == 0) v = (kk < 256) ? w_ih[col*HH + kk]        : w_hh[col*HH + kk - 256];
        else if (g == 1) v = (kk < 256) ? w_ih[(256+col)*HH + kk]  : w_hh[(256+col)*HH + kk - 256];
        else if (g == 2) v = (kk < 256) ? w_ih[(512+col)*HH + kk]  : 0.0f;
        else             v = (kk < 256) ? 0.0f                     : w_hh[(512+col)*HH + kk - 256];
        w8[j] = (_Float16)v;
      }
      *(half8v*)&wp[(size_t)idx*8] = *(half8v*)w8;
    }
    return;
  }
  __shared__ float As[32][64];
  __shared__ float Bs[32][64];
  __shared__ float gws[256];
  int n0 = blockIdx.x*64;
  int m0 = blockIdx.y*64;
  gws[tid] = gcn_w[tid];
  __syncthreads();
  float acc[4][4] = {};
  int tm = tid >> 4, tn = tid & 15;
  const float astep = 2.0f*TA/TS;
  for (int k0 = 0; k0 < 256; k0 += 32){
    #pragma unroll
    for (int r = 0; r < 2; ++r){
      int f = tid + r*256;
      int kk = f >> 4, n4 = (f & 15)*4;
      *(float4*)&Bs[kk][n4] = *(const float4*)&ta_w[(w*256 + k0+kk)*HH + n0 + n4];
    }
    {
      int kk = tid >> 3;
      int mb = (tid & 7)*8;
      float gw = gws[k0 + kk];
      #pragma unroll
      for (int i2 = 0; i2 < 8; ++i2){
        float a = -TA + (float)(m0 + mb + i2)*astep;
        As[kk][mb+i2] = fast_tanh(a*gw);
      }
    }
    __syncthreads();
    #pragma unroll
    for (int kk = 0; kk < 32; ++kk){
      float4 a4 = *(float4*)&As[kk][tm*4];
      float4 b4 = *(float4*)&Bs[kk][tn*4];
      float a[4] = {a4.x,a4.y,a4.z,a4.w};
      float b[4] = {b4.x,b4.y,b4.z,b4.w};
      #pragma unroll
      for (int i = 0; i < 4; ++i)
        #pragma unroll
        for (int j = 0; j < 4; ++j)
          acc[i][j] = fmaf(a[i], b[j], acc[i][j]);
    }
    __syncthreads();
  }
  #pragma unroll
  for (int i = 0; i < 4; ++i){
    int row = m0 + tm*4 + i;
    if (row <= TS){
      #pragma unroll
      for (int j = 0; j < 4; ++j){
        int h = n0 + tn*4 + j;
        _Float16 v = (_Float16)acc[i][j];
        size_t base = ((size_t)w*(TS+1) + row)*HH + h;
        tabp[base*2 + 0] = v;                              // [row].x
        if (row > 0) tabp[(base - HH)*2 + 1] = v;          // [row-1].y
      }
    }
  }
}

// ---------------- THE persistent cooperative step kernel ----------------
// 256 blocks x 1024 threads, cooperative. Block owns nodes [16b,16b+16) for
// ALL 10 steps; h state lives entirely in LDS (fp32 master + fp16 hi/lo
// planes). Cross-block data per step = 16 KB of ring pred values, made
// visible by grid.sync(). 1 dispatch replaces 10.
__global__ __launch_bounds__(1024, 8) void k_steps(
    const int* __restrict__ rowst, const int* __restrict__ csr_src,
    const float* __restrict__ csr_cf, const float* __restrict__ deg,
    float* __restrict__ ring, const _Float16* __restrict__ tabp,
    const float* __restrict__ ta_b, const _Float16* __restrict__ wp,
    const float* __restrict__ b_ih, const float* __restrict__ b_hh,
    const float* __restrict__ out_w, const float* __restrict__ out_b,
    float* __restrict__ out){

  cg::grid_group gg = cg::this_grid();

  __shared__ __align__(16) _Float16 Xh[64][17][8];   // 17-row pad spreads banks
  __shared__ __align__(16) _Float16 Xl[64][17][8];
  __shared__ __align__(16) float h_pad[16][260];     // fp32 h master state
  __shared__ int   ioffs[16][12];                    // pair-table byte offsets
  __shared__ float sfrac[16][12];

  const int tid = threadIdx.x;
  const int n0 = blockIdx.x*16;
  const int wv = tid >> 6, lane = tid & 63;
  const size_t fbase = (size_t)wv*64 + lane;   // + ks*4096 + g*1024

  // ---- zero h state (fp32 + fp16 planes, koct 32..63) ----
  {
    int row = tid >> 6;           // 0..15
    int c0 = (tid & 63)*4;        // 0..252
    *(float4*)&h_pad[row][c0] = make_float4(0.f,0.f,0.f,0.f);
    int koct = 32 + (c0 >> 3), elem = c0 & 7;
    _Float16 z4[4] = {(_Float16)0.f,(_Float16)0.f,(_Float16)0.f,(_Float16)0.f};
    *(half4v*)&Xh[koct][row][elem] = *(half4v*)z4;
    *(half4v*)&Xl[koct][row][elem] = *(half4v*)z4;
  }
  __syncthreads();

  half8v b0[2], b1[2], b2[2];

#define LOADB(KS, BUF)                                                        \
  {                                                                           \
    const int G2v = ((KS) < 8) ? 2 : 3;                                       \
    const size_t fb = fbase + (size_t)(KS)*4096;                              \
    b0[BUF] = *(const half8v*)&wp[fb*8];                                      \
    b1[BUF] = *(const half8v*)&wp[(fb + 1024)*8];                             \
    b2[BUF] = *(const half8v*)&wp[(fb + (size_t)G2v*1024)*8];                 \
  }

  for (int s = 0; s < PP; ++s){
    LOADB(0, 0)   // in flight across the gather+lerp phases

    // ---- CSR gather: wave wv owns node n0+wv; 48 lanes = 12 w x 4 groups ----
    if (lane < 48){
      int w = lane >> 2, g = lane & 3;
      int node = n0 + wv;
      float acc0 = 0.0f;
      if (g == 0){
        float dv2 = 1.0f/(deg[node] + 1.0f);     // dv*dv
        acc0 = dv2*ring[(size_t)node*RS + s + w];
      }
      int e1 = rowst[node+1];
      for (int e = rowst[node] + g; e < e1; e += 4)
        acc0 += csr_cf[e]*ring[(size_t)csr_src[e]*RS + s + w];
      acc0 += __shfl_xor(acc0, 1, 64);
      acc0 += __shfl_xor(acc0, 2, 64);
      if (g == 0){
        float u = (acc0 + TA) * ((float)TS/(2.0f*TA));
        u = fminf(fmaxf(u, 0.0f), (float)TS - 0.0005f);
        int i = (int)u;
        ioffs[wv][w] = (int)((((unsigned)w*(TS+1) + (unsigned)i)*HH)*4u);
        sfrac[wv][w] = u - (float)i;
      }
    }
    __syncthreads();

    // ---- table lerp (pair-table, 1 dword/lerp) -> fp16 hi/lo planes ----
    {
      int col = tid & 255;
      int r0 = (tid >> 8)*4;
      int koct = col >> 3, elem = col & 7;
      float tb = ta_b[col];
      const char* tb_base = (const char*)tabp;
      #pragma unroll
      for (int rr = 0; rr < 4; ++rr){
        int r = r0 + rr;
        float acc0 = tb;
        #pragma unroll
        for (int w = 0; w < 12; ++w){
          unsigned pp = *(const unsigned*)(tb_base + ioffs[r][w] + col*4);
          _Float16 p2[2];
          *(unsigned*)p2 = pp;
          float v0 = (float)p2[0], v1 = (float)p2[1];
          acc0 += v0 + sfrac[r][w]*(v1 - v0);
        }
        float tv = acc0 > 0.0f ? acc0 : 0.0f;
        _Float16 hh_ = (_Float16)tv;
        Xh[koct][r][elem] = hh_;
        Xl[koct][r][elem] = (_Float16)(tv - (float)hh_);
      }
    }
    __syncthreads();

    // ---- GRU MFMA: wave wv owns col-tile wv (16 cols) x 16 rows, K=512 ----
    f32x4 acc[4];
    #pragma unroll
    for (int g = 0; g < 4; ++g) acc[g] = (f32x4){0.f,0.f,0.f,0.f};

    const int a_row = lane & 15, a_ko = lane >> 4;

    #pragma unroll
    for (int ks = 0; ks < 16; ++ks){
      const int cur = ks & 1, nxt = cur ^ 1;
      if (ks < 15) LOADB(ks+1, nxt)
      half8v ah = *(const half8v*)&Xh[ks*4 + a_ko][a_row][0];
      half8v al = *(const half8v*)&Xl[ks*4 + a_ko][a_row][0];
      const int G2 = (ks < 8) ? 2 : 3;
      acc[0]  = __builtin_amdgcn_mfma_f32_16x16x32_f16(ah, b0[cur], acc[0], 0,0,0);
      acc[0]  = __builtin_amdgcn_mfma_f32_16x16x32_f16(al, b0[cur], acc[0], 0,0,0);
      acc[1]  = __builtin_amdgcn_mfma_f32_16x16x32_f16(ah, b1[cur], acc[1], 0,0,0);
      acc[1]  = __builtin_amdgcn_mfma_f32_16x16x32_f16(al, b1[cur], acc[1], 0,0,0);
      acc[G2] = __builtin_amdgcn_mfma_f32_16x16x32_f16(ah, b2[cur], acc[G2], 0,0,0);
      acc[G2] = __builtin_amdgcn_mfma_f32_16x16x32_f16(al, b2[cur], acc[G2], 0,0,0);
    }
    __syncthreads();

    // ---- epilogue: gates + h' -> h_pad + fp16 planes (all LDS, no global) ----
    {
      const int ecl  = lane & 15;
      const int erow = (lane >> 4)*4;
      const int col  = wv*16 + ecl;
      float br  = b_ih[col]        + b_hh[col];
      float bz  = b_ih[col + HH]   + b_hh[col + HH];
      float bxn = b_ih[col + 2*HH];
      float bhn = b_hh[col + 2*HH];
      const int koct = 32 + (col >> 3), elem = col & 7;
      #pragma unroll
      for (int q = 0; q < 4; ++q){
        int row = erow + q;
        float r = fast_sigmoid(acc[0][q] + br);
        float z = fast_sigmoid(acc[1][q] + bz);
        float n = fast_tanh(acc[2][q] + bxn + r*(acc[3][q] + bhn));
        float hv = h_pad[row][col];
        float hp = (1.0f - z)*n + z*hv;
        h_pad[row][col] = hp;
        _Float16 hh16 = (_Float16)hp;
        Xh[koct][row][elem] = hh16;
        Xl[koct][row][elem] = (_Float16)(hp - (float)hh16);
      }
    }
    __syncthreads();

    // ---- pred: wave wv owns row wv; h' . out_w + out_b -> out, ring ----
    {
      int c0 = lane*4;
      float4 hv = *(const float4*)&h_pad[wv][c0];
      float4 w4 = *(const float4*)(out_w + c0);
      float sacc = hv.x*w4.x + hv.y*w4.y + hv.z*w4.z + hv.w*w4.w;
      sacc += __shfl_xor(sacc, 1, 64);
      sacc += __shfl_xor(sacc, 2, 64);
      sacc += __shfl_xor(sacc, 4, 64);
      sacc += __shfl_xor(sacc, 8, 64);
      sacc += __shfl_xor(sacc, 16, 64);
      sacc += __shfl_xor(sacc, 32, 64);
      if (lane == 0){
        float pv = sacc + out_b[0];
        out[(size_t)(n0+wv)*PP + s] = pv;
        ring[(size_t)(n0+wv)*RS + 12 + s] = pv;
      }
    }
    __threadfence();   // flush ring writes to device scope before the grid sync
    gg.sync();         // cross-block (cross-XCD) visibility for next gather
  }
#undef LOADB
}

// ---------------- launcher ----------------

extern "C" void kernel_launch(void* const* d_in, const int* in_sizes, int n_in,
                              void* d_out, int out_size, void* d_ws, size_t ws_size,
                              hipStream_t stream){
  const float* x     = (const float*)d_in[0];
  const int*   ei    = (const int*)  d_in[1];
  const float* ew    = (const float*)d_in[2];
  const float* gcn_w = (const float*)d_in[3];
  const float* ta_w  = (const float*)d_in[4];
  const float* ta_b  = (const float*)d_in[5];
  const float* w_ih  = (const float*)d_in[6];
  const float* w_hh  = (const float*)d_in[7];
  const float* b_ih  = (const float*)d_in[8];
  const float* b_hh  = (const float*)d_in[9];
  const float* out_w = (const float*)d_in[10];
  const float* out_b = (const float*)d_in[11];
  float* out = (float*)d_out;

  char* p = (char*)d_ws;
  _Float16* tabp    = (_Float16*)p; p += (size_t)12*(TS+1)*HH*4; // 2.37 MB pair table
  int*      keys    = (int*)p;      p += (size_t)HS*4;
  int*      midx    = (int*)p;      p += (size_t)HS*4;
  int*      wsrc    = (int*)p;      p += (size_t)EE*4;
  int*      wdst    = (int*)p;      p += (size_t)EE*4;
  float*    wwt     = (float*)p;    p += (size_t)EE*4;
  int*      csr_src = (int*)p;      p += (size_t)EE*4;
  float*    csr_cf  = (float*)p;    p += (size_t)EE*4;
  float*    deg     = (float*)p;    p += (size_t)NN*4;
  int*      cnt     = (int*)p;      p += (size_t)NN*4;
  int*      fill    = (int*)p;      p += (size_t)NN*4;
  int*      rowst   = (int*)p;      p += (size_t)(NN+64)*4;
  int*      count   = (int*)p;      p += 256;
  float*    ring    = (float*)p;    p += (size_t)NN*RS*4;
  _Float16* wp      = (_Float16*)p; p += (size_t)16*4*16*64*8*2; // 1 MB

  k_init   <<<1024, 256, 0, stream>>>(x, keys, midx, deg, cnt, ring, count);
  k_insert <<<EE/256, 256, 0, stream>>>(ei, keys, midx);
  k_compact<<<EE/256, 256, 0, stream>>>(ei, ew, keys, midx, wsrc, wdst, wwt, deg, cnt, count);
  k_scan   <<<1, 1024, 0, stream>>>(cnt, rowst, fill);
  k_scatter<<<EE/256, 256, 0, stream>>>(wsrc, wdst, wwt, deg, fill, csr_src, csr_cf, count);
  k_tab    <<<dim3(HH/64, (TS+64)/64, WW+1), 256, 0, stream>>>(gcn_w, ta_w, w_ih, w_hh, tabp, wp);

  void* kargs[] = {
    (void*)&rowst, (void*)&csr_src, (void*)&csr_cf, (void*)&deg,
    (void*)&ring,  (void*)&tabp,    (void*)&ta_b,   (void*)&wp,
    (void*)&b_ih,  (void*)&b_hh,    (void*)&out_w,  (void*)&out_b,
    (void*)&out
  };
  hipLaunchCooperativeKernel((void*)k_steps, dim3(NBLK), dim3(1024),
                             kargs, 0, stream);
}

// Round 15
// 295.189 us; speedup vs baseline: 8.0422x; 8.0422x over previous
//
#include <hip/hip_runtime.h>
#include <math.h>

#define NN 4096
#define WW 12
#define HH 256
#define PP 10
#define EE 131072
#define HS 262144
#define HMASK (HS-1)
#define TS 192           // table intervals; pair-table = 2.37 MB, L2-resident
#define TA 8.0f          // table half-domain: a in [-TA, TA]
#define RS 22            // ring stride: 12 init cols + 10 pred cols (append-only)

typedef __attribute__((ext_vector_type(8))) _Float16 half8v;  // 8 x fp16 (A/B frag)
typedef __attribute__((ext_vector_type(4))) _Float16 half4v;
typedef __attribute__((ext_vector_type(4))) float f32x4;      // C/D frag

__device__ __forceinline__ float fast_tanh(float x){
  float e = __expf(2.0f*x);
  return 1.0f - 2.0f/(e+1.0f);   // exact identity (e^2x-1)/(e^2x+1)
}
__device__ __forceinline__ float fast_sigmoid(float x){
  return 1.0f/(1.0f+__expf(-x));
}

// ---------------- setup kernels ----------------

__global__ void k_init(const float* __restrict__ x, int* keys, int* midx,
                       float* deg, int* cnt, float* ring, float* hA, int* count){
  int t = blockIdx.x*256 + threadIdx.x;        // 262144 threads
  int i4 = t*4;
  if (i4 < HS){
    int4 m1 = make_int4(-1,-1,-1,-1);
    *(int4*)&keys[i4] = m1;
    *(int4*)&midx[i4] = m1;
  }
  if (i4 < NN*HH) *(float4*)&hA[i4] = make_float4(0.f,0.f,0.f,0.f);
  if (i4 < NN*WW){
    #pragma unroll
    for (int j = 0; j < 4; ++j){
      int i = i4 + j;
      int n = i/WW, w = i - n*WW;
      ring[n*RS + w] = x[i];
    }
  }
  if (t < NN){ deg[t] = 0.0f; cnt[t] = 0; }
  if (t == 0) *count = 0;
}

// dedupe: numpy fancy assignment => last (max-index) edge wins per (src,dst)
__global__ void k_insert(const int* __restrict__ ei, int* keys, int* midx){
  int e = blockIdx.x*256 + threadIdx.x;
  if (e >= EE) return;
  int key = ei[e]*NN + ei[EE+e];
  unsigned h = (((unsigned)key)*2654435761u >> 14) & HMASK;
  for(;;){
    int k = keys[h];
    if (k == key){ atomicMax(&midx[h], e); return; }
    if (k == -1){
      int old = atomicCAS(&keys[h], -1, key);
      if (old == -1 || old == key){ atomicMax(&midx[h], e); return; }
    }
    h = (h+1) & HMASK;
  }
}

__global__ void k_compact(const int* __restrict__ ei, const float* __restrict__ ew,
                          const int* __restrict__ keys, const int* __restrict__ midx,
                          int* wsrc, int* wdst, float* wwt,
                          float* deg, int* cnt, int* count){
  int e = blockIdx.x*256 + threadIdx.x;
  if (e >= EE) return;
  int src = ei[e], dst = ei[EE+e];
  int key = src*NN + dst;
  unsigned h = (((unsigned)key)*2654435761u >> 14) & HMASK;
  while (keys[h] != key) h = (h+1) & HMASK;
  if (midx[h] == e){            // this edge is the winner for (src,dst)
    int p = atomicAdd(count, 1);
    wsrc[p] = src; wdst[p] = dst; wwt[p] = ew[e];
    atomicAdd(&deg[src], ew[e]);
    atomicAdd(&cnt[dst], 1);
  }
}

__global__ __launch_bounds__(1024) void k_scan(const int* __restrict__ cnt,
                                               int* row_start, int* fill){
  __shared__ int sd[NN];
  int tid = threadIdx.x;
  for (int i = tid; i < NN; i += 1024) sd[i] = cnt[i];
  __syncthreads();
  for (int off = 1; off < NN; off <<= 1){
    int v[4];
    #pragma unroll
    for (int r = 0; r < 4; ++r){
      int i = tid + r*1024;
      v[r] = (i >= off) ? sd[i-off] : 0;
    }
    __syncthreads();
    #pragma unroll
    for (int r = 0; r < 4; ++r) sd[tid + r*1024] += v[r];
    __syncthreads();
  }
  for (int i = tid; i < NN; i += 1024){
    int incl = sd[i];
    row_start[i+1] = incl;
    fill[i] = incl - cnt[i];
  }
  if (tid == 0) row_start[0] = 0;
}

// scatter + inline coef = wwt * d[src] * d[dst], d = 1/sqrt(deg+1)
__global__ void k_scatter(const int* __restrict__ wsrc, const int* __restrict__ wdst,
                          const float* __restrict__ wwt, const float* __restrict__ deg,
                          int* fill, int* csr_src, float* csr_cf,
                          const int* __restrict__ count){
  int p = blockIdx.x*256 + threadIdx.x;
  if (p >= *count) return;
  int s = wsrc[p], d = wdst[p];
  float c = wwt[p] * (1.0f/sqrtf(deg[s]+1.0f)) * (1.0f/sqrtf(deg[d]+1.0f));
  int pos = atomicAdd(&fill[d], 1);
  csr_src[pos] = s;
  csr_cf[pos] = c;
}

// table build (z<12) + weight pack (z==12), fused into one dispatch.
// tabp layout: [w][s][h] pair (f16 tab[s][h], f16 tab[s+1][h]) -> 4 B/entry.
__global__ __launch_bounds__(256) void k_tab(const float* __restrict__ gcn_w,
                                             const float* __restrict__ ta_w,
                                             const float* __restrict__ w_ih,
                                             const float* __restrict__ w_hh,
                                             _Float16* __restrict__ tabp,
                                             _Float16* __restrict__ wp){
  int tid = threadIdx.x;
  int w  = blockIdx.z;
  if (w == 12){
    // ---- weight pack: 16 slice-blocks x 256 thr x 16 octets ----
    int sb = blockIdx.y*4 + blockIdx.x;       // 0..15
    #pragma unroll
    for (int k = 0; k < 16; ++k){
      int idx = sb*4096 + k*256 + tid;
      int lane = idx & 63;
      int rest = idx >> 6;
      int ct = rest & 15; rest >>= 4;
      int g  = rest & 3;
      int ks = rest >> 2;
      int col = ct*16 + (lane & 15);
      int kb  = ks*32 + (lane >> 4)*8;
      _Float16 w8[8];
      #pragma unroll
      for (int j = 0; j < 8; ++j){
        int kk = kb + j;
        float v;
        if      (g == 0) v = (kk < 256) ? w_ih[col*HH + kk]        : w_hh[col*HH + kk - 256];
        else if (g == 1) v = (kk < 256) ? w_ih[(256+col)*HH + kk]  : w_hh[(256+col)*HH + kk - 256];
        else if (g == 2) v = (kk < 256) ? w_ih[(512+col)*HH + kk]  : 0.0f;
        else             v = (kk < 256) ? 0.0f                     : w_hh[(512+col)*HH + kk - 256];
        w8[j] = (_Float16)v;
      }
      *(half8v*)&wp[(size_t)idx*8] = *(half8v*)w8;
    }
    return;
  }
  __shared__ float As[32][64];
  __shared__ float Bs[32][64];
  __shared__ float gws[256];
  int n0 = blockIdx.x*64;
  int m0 = blockIdx.y*64;
  gws[tid] = gcn_w[tid];
  __syncthreads();
  float acc[4][4] = {};
  int tm = tid >> 4, tn = tid & 15;
  const float astep = 2.0f*TA/TS;
  for (int k0 = 0; k0 < 256; k0 += 32){
    #pragma unroll
    for (int r = 0; r < 2; ++r){
      int f = tid + r*256;
      int kk = f >> 4, n4 = (f & 15)*4;
      *(float4*)&Bs[kk][n4] = *(const float4*)&ta_w[(w*256 + k0+kk)*HH + n0 + n4];
    }
    {
      int kk = tid >> 3;
      int mb = (tid & 7)*8;
      float gw = gws[k0 + kk];
      #pragma unroll
      for (int i2 = 0; i2 < 8; ++i2){
        float a = -TA + (float)(m0 + mb + i2)*astep;
        As[kk][mb+i2] = fast_tanh(a*gw);
      }
    }
    __syncthreads();
    #pragma unroll
    for (int kk = 0; kk < 32; ++kk){
      float4 a4 = *(float4*)&As[kk][tm*4];
      float4 b4 = *(float4*)&Bs[kk][tn*4];
      float a[4] = {a4.x,a4.y,a4.z,a4.w};
      float b[4] = {b4.x,b4.y,b4.z,b4.w};
      #pragma unroll
      for (int i = 0; i < 4; ++i)
        #pragma unroll
        for (int j = 0; j < 4; ++j)
          acc[i][j] = fmaf(a[i], b[j], acc[i][j]);
    }
    __syncthreads();
  }
  #pragma unroll
  for (int i = 0; i < 4; ++i){
    int row = m0 + tm*4 + i;
    if (row <= TS){
      #pragma unroll
      for (int j = 0; j < 4; ++j){
        int h = n0 + tn*4 + j;
        _Float16 v = (_Float16)acc[i][j];
        size_t base = ((size_t)w*(TS+1) + row)*HH + h;
        tabp[base*2 + 0] = v;                              // [row].x
        if (row > 0) tabp[(base - HH)*2 + 1] = v;          // [row-1].y
      }
    }
  }
}

// ---------------- the per-step kernel ----------------
// 256 blocks x 1024 threads (1 block/CU); block owns nodes [16b,16b+16).
// B-fragments in a DEPTH-4 register pipeline (slot = ks&3): ~3 iterations of
// L2 latency cover instead of 1. First 4 LOADBs issued at kernel entry so
// they fly during the gather+lerp phases.
__global__ __launch_bounds__(1024, 4) void k_step(
    const int* __restrict__ rowst, const int* __restrict__ csr_src,
    const float* __restrict__ csr_cf, const float* __restrict__ deg,
    float* __restrict__ ring, const _Float16* __restrict__ tabp,
    const float* __restrict__ ta_b,
    const float* __restrict__ hc, float* __restrict__ hnb,
    const _Float16* __restrict__ wp,
    const float* __restrict__ b_ih, const float* __restrict__ b_hh,
    const float* __restrict__ out_w, const float* __restrict__ out_b,
    float* __restrict__ out, int s){

  __shared__ __align__(16) _Float16 Xh[64][17][8];   // 17-row pad spreads banks
  __shared__ __align__(16) _Float16 Xl[64][17][8];
  __shared__ __align__(16) float h_pad[16][260];     // fp32 h for epilogue + pred
  __shared__ int   ioffs[16][12];                    // pair-table byte offsets
  __shared__ float sfrac[16][12];

  const int tid = threadIdx.x;
  const int n0 = blockIdx.x*16;
  const int wv = tid >> 6, lane = tid & 63;

  const size_t fbase = (size_t)wv*64 + lane;   // + ks*4096 + g*1024
  half8v b0[4], b1[4], b2[4];

#define LOADB(KS, BUF)                                                        \
  {                                                                           \
    const int G2v = ((KS) < 8) ? 2 : 3;                                       \
    const size_t fb = fbase + (size_t)(KS)*4096;                              \
    b0[BUF] = *(const half8v*)&wp[fb*8];                                      \
    b1[BUF] = *(const half8v*)&wp[(fb + 1024)*8];                             \
    b2[BUF] = *(const half8v*)&wp[(fb + (size_t)G2v*1024)*8];                 \
  }

  LOADB(0, 0)   // depth-4 pipeline primed before the gather+lerp phases
  LOADB(1, 1)
  LOADB(2, 2)
  LOADB(3, 3)

  // ---- stage hc -> LDS fp32 + fp16 hi/lo planes (koct 32..63) ----
  {
    int row = tid >> 6;           // 0..15
    int c0 = (tid & 63)*4;        // 0..252
    float4 v = *(const float4*)(hc + (size_t)(n0+row)*HH + c0);
    *(float4*)&h_pad[row][c0] = v;
    float f[4] = {v.x,v.y,v.z,v.w};
    _Float16 h4[4], l4[4];
    #pragma unroll
    for (int j = 0; j < 4; ++j){
      h4[j] = (_Float16)f[j];
      l4[j] = (_Float16)(f[j] - (float)h4[j]);
    }
    int koct = 32 + (c0 >> 3), elem = c0 & 7;
    *(half4v*)&Xh[koct][row][elem] = *(half4v*)h4;
    *(half4v*)&Xl[koct][row][elem] = *(half4v*)l4;
  }
  // ---- CSR gather: wave wv owns node n0+wv; 48 lanes = 12 w x 4 edge-groups ----
  if (lane < 48){
    int w = lane >> 2, g = lane & 3;
    int node = n0 + wv;
    float acc0 = 0.0f;
    if (g == 0){
      float dv2 = 1.0f/(deg[node] + 1.0f);     // dv*dv
      acc0 = dv2*ring[(size_t)node*RS + s + w];
    }
    int e1 = rowst[node+1];
    for (int e = rowst[node] + g; e < e1; e += 4)
      acc0 += csr_cf[e]*ring[(size_t)csr_src[e]*RS + s + w];
    acc0 += __shfl_xor(acc0, 1, 64);
    acc0 += __shfl_xor(acc0, 2, 64);
    if (g == 0){
      float u = (acc0 + TA) * ((float)TS/(2.0f*TA));
      u = fminf(fmaxf(u, 0.0f), (float)TS - 0.0005f);
      int i = (int)u;
      ioffs[wv][w] = (int)((((unsigned)w*(TS+1) + (unsigned)i)*HH)*4u);  // byte off
      sfrac[wv][w] = u - (float)i;
    }
  }
  __syncthreads();

  // ---- table lerp (pair-table, 1 dword/lerp) -> fp16 hi/lo planes ----
  {
    int col = tid & 255;
    int r0 = (tid >> 8)*4;
    int koct = col >> 3, elem = col & 7;
    float tb = ta_b[col];
    const char* tb_base = (const char*)tabp;
    #pragma unroll
    for (int rr = 0; rr < 4; ++rr){
      int r = r0 + rr;
      float acc0 = tb;
      #pragma unroll
      for (int w = 0; w < 12; ++w){
        unsigned pp = *(const unsigned*)(tb_base + ioffs[r][w] + col*4);
        _Float16 p2[2];
        *(unsigned*)p2 = pp;
        float v0 = (float)p2[0], v1 = (float)p2[1];
        acc0 += v0 + sfrac[r][w]*(v1 - v0);
      }
      float tv = acc0 > 0.0f ? acc0 : 0.0f;
      _Float16 hh_ = (_Float16)tv;
      Xh[koct][r][elem] = hh_;
      Xl[koct][r][elem] = (_Float16)(tv - (float)hh_);
    }
  }
  __syncthreads();

  // ---- GRU MFMA: wave wv owns col-tile wv (16 cols) x 16 rows, K=512 ----
  f32x4 acc[4];
  #pragma unroll
  for (int g = 0; g < 4; ++g) acc[g] = (f32x4){0.f,0.f,0.f,0.f};

  const int a_row = lane & 15, a_ko = lane >> 4;

  #pragma unroll
  for (int ks = 0; ks < 16; ++ks){
    const int cur = ks & 3;
    half8v ah = *(const half8v*)&Xh[ks*4 + a_ko][a_row][0];
    half8v al = *(const half8v*)&Xl[ks*4 + a_ko][a_row][0];
    const int G2 = (ks < 8) ? 2 : 3;
    acc[0]  = __builtin_amdgcn_mfma_f32_16x16x32_f16(ah, b0[cur], acc[0], 0,0,0);
    acc[0]  = __builtin_amdgcn_mfma_f32_16x16x32_f16(al, b0[cur], acc[0], 0,0,0);
    acc[1]  = __builtin_amdgcn_mfma_f32_16x16x32_f16(ah, b1[cur], acc[1], 0,0,0);
    acc[1]  = __builtin_amdgcn_mfma_f32_16x16x32_f16(al, b1[cur], acc[1], 0,0,0);
    acc[G2] = __builtin_amdgcn_mfma_f32_16x16x32_f16(ah, b2[cur], acc[G2], 0,0,0);
    acc[G2] = __builtin_amdgcn_mfma_f32_16x16x32_f16(al, b2[cur], acc[G2], 0,0,0);
    if (ks < 12) LOADB(ks+4, cur)   // refill freed slot, ~3 iterations ahead
  }
#undef LOADB
  __syncthreads();

  // ---- epilogue: gates + h' -> global hnb + h_pad (reused for pred) ----
  {
    const int ecl  = lane & 15;
    const int erow = (lane >> 4)*4;
    const int col  = wv*16 + ecl;
    float br  = b_ih[col]        + b_hh[col];
    float bz  = b_ih[col + HH]   + b_hh[col + HH];
    float bxn = b_ih[col + 2*HH];
    float bhn = b_hh[col + 2*HH];
    #pragma unroll
    for (int q = 0; q < 4; ++q){
      int row = erow + q;
      float r = fast_sigmoid(acc[0][q] + br);
      float z = fast_sigmoid(acc[1][q] + bz);
      float n = fast_tanh(acc[2][q] + bxn + r*(acc[3][q] + bhn));
      float hv = h_pad[row][col];
      float hp = (1.0f - z)*n + z*hv;
      hnb[(size_t)(n0+row)*HH + col] = hp;
      h_pad[row][col] = hp;
    }
  }
  __syncthreads();

  // ---- pred: wave wv owns row wv; h' . out_w + out_b -> out, ring ----
  {
    int c0 = lane*4;
    float4 hv = *(const float4*)&h_pad[wv][c0];
    float4 w4 = *(const float4*)(out_w + c0);
    float sacc = hv.x*w4.x + hv.y*w4.y + hv.z*w4.z + hv.w*w4.w;
    sacc += __shfl_xor(sacc, 1, 64);
    sacc += __shfl_xor(sacc, 2, 64);
    sacc += __shfl_xor(sacc, 4, 64);
    sacc += __shfl_xor(sacc, 8, 64);
    sacc += __shfl_xor(sacc, 16, 64);
    sacc += __shfl_xor(sacc, 32, 64);
    if (lane == 0){
      float pv = sacc + out_b[0];
      out[(size_t)(n0+wv)*PP + s] = pv;
      ring[(size_t)(n0+wv)*RS + 12 + s] = pv;
    }
  }
}

// ---------------- launcher ----------------

extern "C" void kernel_launch(void* const* d_in, const int* in_sizes, int n_in,
                              void* d_out, int out_size, void* d_ws, size_t ws_size,
                              hipStream_t stream){
  const float* x     = (const float*)d_in[0];
  const int*   ei    = (const int*)  d_in[1];
  const float* ew    = (const float*)d_in[2];
  const float* gcn_w = (const float*)d_in[3];
  const float* ta_w  = (const float*)d_in[4];
  const float* ta_b  = (const float*)d_in[5];
  const float* w_ih  = (const float*)d_in[6];
  const float* w_hh  = (const float*)d_in[7];
  const float* b_ih  = (const float*)d_in[8];
  const float* b_hh  = (const float*)d_in[9];
  const float* out_w = (const float*)d_in[10];
  const float* out_b = (const float*)d_in[11];
  float* out = (float*)d_out;

  char* p = (char*)d_ws;
  _Float16* tabp    = (_Float16*)p; p += (size_t)12*(TS+1)*HH*4; // 2.37 MB pair table
  int*      keys    = (int*)p;      p += (size_t)HS*4;
  int*      midx    = (int*)p;      p += (size_t)HS*4;
  int*      wsrc    = (int*)p;      p += (size_t)EE*4;
  int*      wdst    = (int*)p;      p += (size_t)EE*4;
  float*    wwt     = (float*)p;    p += (size_t)EE*4;
  int*      csr_src = (int*)p;      p += (size_t)EE*4;
  float*    csr_cf  = (float*)p;    p += (size_t)EE*4;
  float*    deg     = (float*)p;    p += (size_t)NN*4;
  int*      cnt     = (int*)p;      p += (size_t)NN*4;
  int*      fill    = (int*)p;      p += (size_t)NN*4;
  int*      rowst   = (int*)p;      p += (size_t)(NN+64)*4;
  int*      count   = (int*)p;      p += 256;
  float*    ring    = (float*)p;    p += (size_t)NN*RS*4;
  float*    hA      = (float*)p;    p += (size_t)NN*HH*4;
  float*    hB      = (float*)p;    p += (size_t)NN*HH*4;
  _Float16* wp      = (_Float16*)p; p += (size_t)16*4*16*64*8*2; // 1 MB

  k_init   <<<1024, 256, 0, stream>>>(x, keys, midx, deg, cnt, ring, hA, count);
  k_insert <<<EE/256, 256, 0, stream>>>(ei, keys, midx);
  k_compact<<<EE/256, 256, 0, stream>>>(ei, ew, keys, midx, wsrc, wdst, wwt, deg, cnt, count);
  k_scan   <<<1, 1024, 0, stream>>>(cnt, rowst, fill);
  k_scatter<<<EE/256, 256, 0, stream>>>(wsrc, wdst, wwt, deg, fill, csr_src, csr_cf, count);
  k_tab    <<<dim3(HH/64, (TS+64)/64, WW+1), 256, 0, stream>>>(gcn_w, ta_w, w_ih, w_hh, tabp, wp);

  for (int s = 0; s < PP; ++s){
    const float* hc  = (s & 1) ? hB : hA;
    float*       hnb = (s & 1) ? hA : hB;
    k_step<<<NN/16, 1024, 0, stream>>>(rowst, csr_src, csr_cf, deg, ring, tabp,
                                       ta_b, hc, hnb, wp,
                                       b_ih, b_hh, out_w, out_b, out, s);
  }
}